// Round 1
// baseline (3857.515 us; speedup 1.0000x reference)
//
#include <hip/hip_runtime.h>
#include <math.h>

#define QS 1024
#define BS 4
#define DD 1024
#define NH 16
#define DHD 64
#define RL 2048
#define SCALEF 0.125f

__device__ __forceinline__ float dot4(float4 a, float4 b) {
  return a.x * b.x + a.y * b.y + a.z * b.z + a.w * b.w;
}

// ---------------- GEMM: C[M,1024] = A[M,1024] @ B ----------------
// BT=false: B is [1024 x 1024] row-major [k][n]   (projection weights (D,N,DH))
// BT=true : B is [1024 x 1024] row-major [n][k]   (C = A * B^T, for o_w)
template <bool BT>
__global__ __launch_bounds__(256) void gemm_f32(const float* __restrict__ A,
                                                const float* __restrict__ Bm,
                                                float* __restrict__ C) {
  __shared__ float As[16][68];
  __shared__ float Bs[16][68];
  const int t = threadIdx.x;
  const int n0 = blockIdx.x * 64;
  const int m0 = blockIdx.y * 64;
  const int ty = t >> 4, tx = t & 15;

  float acc[4][4] = {};

  for (int k0 = 0; k0 < 1024; k0 += 16) {
    {
      int rr = t >> 2, c4 = (t & 3) * 4;
      float4 va = *(const float4*)(A + (size_t)(m0 + rr) * 1024 + k0 + c4);
      As[c4 + 0][rr] = va.x;
      As[c4 + 1][rr] = va.y;
      As[c4 + 2][rr] = va.z;
      As[c4 + 3][rr] = va.w;
    }
    if (!BT) {
      int kr_ = t >> 4, c4 = (t & 15) * 4;
      float4 vb = *(const float4*)(Bm + (size_t)(k0 + kr_) * 1024 + n0 + c4);
      *(float4*)&Bs[kr_][c4] = vb;
    } else {
      int c = t >> 2, k4 = (t & 3) * 4;
      float4 vb = *(const float4*)(Bm + (size_t)(n0 + c) * 1024 + k0 + k4);
      Bs[k4 + 0][c] = vb.x;
      Bs[k4 + 1][c] = vb.y;
      Bs[k4 + 2][c] = vb.z;
      Bs[k4 + 3][c] = vb.w;
    }
    __syncthreads();
#pragma unroll
    for (int k = 0; k < 16; ++k) {
      float4 a = *(float4*)&As[k][ty * 4];
      float4 b = *(float4*)&Bs[k][tx * 4];
      float av_[4] = {a.x, a.y, a.z, a.w};
      float bv_[4] = {b.x, b.y, b.z, b.w};
#pragma unroll
      for (int i = 0; i < 4; i++)
#pragma unroll
        for (int j = 0; j < 4; j++) acc[i][j] += av_[i] * bv_[j];
    }
    __syncthreads();
  }
#pragma unroll
  for (int i = 0; i < 4; i++) {
    float4 o = make_float4(acc[i][0], acc[i][1], acc[i][2], acc[i][3]);
    *(float4*)(C + (size_t)(m0 + ty * 4 + i) * 1024 + n0 + tx * 4) = o;
  }
}

// ------------- fused relative attention core (one stream) -------------
// block = (32 q rows, one b, one n). Online softmax over 32-wide key tiles.
// bd via rel-shift identity: bd[i][j] = (q_i + rrb) . k_r[j + Q - i]
__global__ __launch_bounds__(256) void attn_core(
    const float* __restrict__ qh, const float* __restrict__ khh,
    const float* __restrict__ vhh, const float* __restrict__ krr,
    const float* __restrict__ segm, const float* __restrict__ mask,
    const float* __restrict__ seg_embed, const float* __restrict__ rwb,
    const float* __restrict__ rrb, const float* __restrict__ rsb,
    float* __restrict__ av) {
  const int t = threadIdx.x;
  const int i0 = blockIdx.x * 32;
  const int n = blockIdx.y & 15;
  const int b = blockIdx.y >> 4;

  __shared__ float sqw[32][68];  // q + r_w_bias
  __shared__ float sqr[32][68];  // q + r_r_bias
  __shared__ float skh[32][68];
  __shared__ float sv[32][68];
  __shared__ float skr[64][68];  // sliding window of k_head_r
  __shared__ float ss[32][33];
  __shared__ float sE[32][2];
  __shared__ float smax[32], ssum[32], sfac[32];

  const int lti = t >> 3, ld8 = (t & 7) * 8;

  // load raw q tile
  {
    const float* src = qh + ((size_t)(i0 + lti) * BS + b) * DD + n * DHD + ld8;
    *(float4*)&sqw[lti][ld8] = *(const float4*)src;
    *(float4*)&sqw[lti][ld8 + 4] = *(const float4*)(src + 4);
  }
  if (t < 32) {
    smax[t] = -INFINITY;
    ssum[t] = 0.f;
  }
  __syncthreads();
  // sqr = q + rrb ; E_s = (q + rsb) . seg_embed[s,n,:]
#pragma unroll
  for (int k2 = 0; k2 < 8; ++k2)
    sqr[lti][ld8 + k2] = sqw[lti][ld8 + k2] + rrb[n * DHD + ld8 + k2];
  if (t < 64) {
    int ti = t >> 1, s = t & 1;
    float e = 0.f;
    for (int d = 0; d < DHD; ++d)
      e += (sqw[ti][d] + rsb[n * DHD + d]) * seg_embed[(s * NH + n) * DHD + d];
    sE[ti][s] = e;
  }
  __syncthreads();
#pragma unroll
  for (int k2 = 0; k2 < 8; ++k2) sqw[lti][ld8 + k2] += rwb[n * DHD + ld8 + k2];

  float oacc[8] = {};
  const int tr = t >> 4, tc = t & 15;

  for (int jt = 0; jt < QS / 32; ++jt) {
    const int j0 = jt * 32;
    __syncthreads();  // guard previous iteration's PV reads
    // stage K, V tiles
    {
      const float* s1 = khh + ((size_t)(j0 + lti) * BS + b) * DD + n * DHD + ld8;
      *(float4*)&skh[lti][ld8] = *(const float4*)s1;
      *(float4*)&skh[lti][ld8 + 4] = *(const float4*)(s1 + 4);
      const float* s2 = vhh + ((size_t)(j0 + lti) * BS + b) * DD + n * DHD + ld8;
      *(float4*)&sv[lti][ld8] = *(const float4*)s2;
      *(float4*)&sv[lti][ld8 + 4] = *(const float4*)(s2 + 4);
    }
    // stage k_r window: rows jj = j0 + Q - i0 - 31 + l, l=0..63 (loc used: 0..62)
    {
      int l = t >> 2, d16 = (t & 3) * 16;
      int jj = j0 + QS - i0 - 31 + l;
      if (jj >= 0 && jj < RL) {
        const float* s3 = krr + ((size_t)jj * BS + b) * DD + n * DHD + d16;
#pragma unroll
        for (int k2 = 0; k2 < 4; ++k2)
          *(float4*)&skr[l][d16 + 4 * k2] = *(const float4*)(s3 + 4 * k2);
      }
    }
    __syncthreads();
    // scores: each thread owns pairs (tr,tc),(tr,tc+16),(tr+16,tc),(tr+16,tc+16)
    {
      float a00 = 0, a01 = 0, a10 = 0, a11 = 0;
      const int loc0 = tc - tr + 31;  // local k_r row for (tr,tc)
#pragma unroll
      for (int d4 = 0; d4 < 16; ++d4) {
        const int dc = d4 * 4;
        float4 qw0 = *(float4*)&sqw[tr][dc];
        float4 qw1 = *(float4*)&sqw[tr + 16][dc];
        float4 qr0 = *(float4*)&sqr[tr][dc];
        float4 qr1 = *(float4*)&sqr[tr + 16][dc];
        float4 k0v = *(float4*)&skh[tc][dc];
        float4 k1v = *(float4*)&skh[tc + 16][dc];
        float4 r0v = *(float4*)&skr[loc0 - 16][dc];
        float4 r1v = *(float4*)&skr[loc0][dc];
        float4 r2v = *(float4*)&skr[loc0 + 16][dc];
        a00 += dot4(qw0, k0v) + dot4(qr0, r1v);
        a01 += dot4(qw0, k1v) + dot4(qr0, r2v);
        a10 += dot4(qw1, k0v) + dot4(qr1, r0v);
        a11 += dot4(qw1, k1v) + dot4(qr1, r1v);
      }
#pragma unroll
      for (int pi = 0; pi < 4; ++pi) {
        int ti = (pi & 2) ? tr + 16 : tr;
        int tj = (pi & 1) ? tc + 16 : tc;
        float a = (pi == 0) ? a00 : (pi == 1) ? a01 : (pi == 2) ? a10 : a11;
        size_t gi = (size_t)(i0 + ti), gj = (size_t)(j0 + tj);
        const float* sp = segm + ((gi * QS + gj) * BS + b) * 2;
        float m = mask[(gi * QS + gj) * BS + b];
        float sc =
            (a + sp[0] * sE[ti][0] + sp[1] * sE[ti][1]) * SCALEF - 1e30f * m;
        ss[ti][tj] = sc;
      }
    }
    __syncthreads();
    // online softmax update: 8 threads per row
    {
      int rr = t >> 3, c0 = (t & 7) * 4;
      float v0 = ss[rr][c0], v1 = ss[rr][c0 + 1], v2 = ss[rr][c0 + 2],
            v3 = ss[rr][c0 + 3];
      float mx = fmaxf(fmaxf(v0, v1), fmaxf(v2, v3));
      mx = fmaxf(mx, __shfl_xor(mx, 1));
      mx = fmaxf(mx, __shfl_xor(mx, 2));
      mx = fmaxf(mx, __shfl_xor(mx, 4));
      float mold = smax[rr];
      float mnew = fmaxf(mold, mx);
      float p0 = __expf(v0 - mnew), p1 = __expf(v1 - mnew),
            p2 = __expf(v2 - mnew), p3 = __expf(v3 - mnew);
      ss[rr][c0] = p0;
      ss[rr][c0 + 1] = p1;
      ss[rr][c0 + 2] = p2;
      ss[rr][c0 + 3] = p3;
      float sm = p0 + p1 + p2 + p3;
      sm += __shfl_xor(sm, 1);
      sm += __shfl_xor(sm, 2);
      sm += __shfl_xor(sm, 4);
      if ((t & 7) == 0) {
        float f = __expf(mold - mnew);  // exp(-inf)=0 on first tile
        smax[rr] = mnew;
        ssum[rr] = ssum[rr] * f + sm;
        sfac[rr] = f;
      }
    }
    __syncthreads();
    // PV accumulate: thread owns (row lti, 8 d-columns at ld8)
    {
      float f = sfac[lti];
#pragma unroll
      for (int k2 = 0; k2 < 8; ++k2) oacc[k2] *= f;
      for (int tj = 0; tj < 32; ++tj) {
        float p = ss[lti][tj];
        float4 va = *(float4*)&sv[tj][ld8];
        float4 vb = *(float4*)&sv[tj][ld8 + 4];
        oacc[0] += p * va.x;
        oacc[1] += p * va.y;
        oacc[2] += p * va.z;
        oacc[3] += p * va.w;
        oacc[4] += p * vb.x;
        oacc[5] += p * vb.y;
        oacc[6] += p * vb.z;
        oacc[7] += p * vb.w;
      }
    }
  }
  float inv = 1.f / ssum[lti];
  float4 o1 = make_float4(oacc[0] * inv, oacc[1] * inv, oacc[2] * inv,
                          oacc[3] * inv);
  float4 o2 = make_float4(oacc[4] * inv, oacc[5] * inv, oacc[6] * inv,
                          oacc[7] * inv);
  float* dst = av + ((size_t)(i0 + lti) * BS + b) * DD + n * DHD + ld8;
  *(float4*)dst = o1;
  *(float4*)(dst + 4) = o2;
}

// ------------- residual add + LayerNorm (in-place on io) -------------
__global__ __launch_bounds__(256) void add_ln(float* __restrict__ io,
                                              const float* __restrict__ resid,
                                              const float* __restrict__ gam,
                                              const float* __restrict__ bet) {
  const size_t row = blockIdx.x;
  float* o = io + row * 1024;
  const float* x = resid + row * 1024;
  const int t = threadIdx.x;
  float v[4];
  float s1 = 0.f, s2 = 0.f;
#pragma unroll
  for (int k = 0; k < 4; ++k) {
    int idx = t + 256 * k;
    v[k] = o[idx] + x[idx];
    s1 += v[k];
    s2 += v[k] * v[k];
  }
#pragma unroll
  for (int off = 32; off >= 1; off >>= 1) {
    s1 += __shfl_xor(s1, off);
    s2 += __shfl_xor(s2, off);
  }
  __shared__ float r1[4], r2[4];
  if ((t & 63) == 0) {
    r1[t >> 6] = s1;
    r2[t >> 6] = s2;
  }
  __syncthreads();
  s1 = r1[0] + r1[1] + r1[2] + r1[3];
  s2 = r2[0] + r2[1] + r2[2] + r2[3];
  float mean = s1 * (1.f / 1024.f);
  float var = s2 * (1.f / 1024.f) - mean * mean;
  float rstd = rsqrtf(fmaxf(var, 0.f) + 1e-12f);
#pragma unroll
  for (int k = 0; k < 4; ++k) {
    int idx = t + 256 * k;
    o[idx] = (v[k] - mean) * rstd * gam[idx] + bet[idx];
  }
}

extern "C" void kernel_launch(void* const* d_in, const int* in_sizes, int n_in,
                              void* d_out, int out_size, void* d_ws,
                              size_t ws_size, hipStream_t stream) {
  const float* h = (const float*)d_in[0];
  const float* g = (const float*)d_in[1];
  const float* mh = (const float*)d_in[2];
  const float* mg = (const float*)d_in[3];
  const float* r = (const float*)d_in[4];
  const float* seg = (const float*)d_in[5];
  const float* q_w = (const float*)d_in[6];
  const float* k_w = (const float*)d_in[7];
  const float* v_w = (const float*)d_in[8];
  const float* o_w = (const float*)d_in[9];
  const float* r_w = (const float*)d_in[10];
  const float* rrb = (const float*)d_in[11];
  const float* rsb = (const float*)d_in[12];
  const float* rwb = (const float*)d_in[13];
  const float* se = (const float*)d_in[14];
  const float* gam = (const float*)d_in[15];
  const float* bet = (const float*)d_in[16];
  float* out = (float*)d_out;
  float* ws = (float*)d_ws;

  // ws layout (floats): q (4M), k_h (4M), v_h (4M), k_r (8M), av (4M) = 100.7MB
  const size_t SZ1 = (size_t)4096 * 1024;
  float* qbuf = ws;
  float* khb = ws + SZ1;
  float* vhb = ws + 2 * SZ1;
  float* krb = ws + 3 * SZ1;  // occupies 2*SZ1
  float* avb = ws + 5 * SZ1;

  dim3 blk(256);
  dim3 gp(16, 64);   // GEMM M=4096
  dim3 gr(16, 128);  // GEMM M=8192
  dim3 ga(32, 64);   // attention: 32 q-tiles x (b*16+n)

  // shared projections
  gemm_f32<false><<<gp, blk, 0, stream>>>(h, k_w, khb);
  gemm_f32<false><<<gp, blk, 0, stream>>>(h, v_w, vhb);
  gemm_f32<false><<<gr, blk, 0, stream>>>(r, r_w, krb);

  // content stream
  gemm_f32<false><<<gp, blk, 0, stream>>>(h, q_w, qbuf);
  attn_core<<<ga, blk, 0, stream>>>(qbuf, khb, vhb, krb, seg, mh, se, rwb, rrb,
                                    rsb, avb);
  gemm_f32<true><<<gp, blk, 0, stream>>>(avb, o_w, out);
  add_ln<<<dim3(4096), blk, 0, stream>>>(out, h, gam, bet);

  // query stream (reuses qbuf/avb; same-stream serialization makes this safe)
  gemm_f32<false><<<gp, blk, 0, stream>>>(g, q_w, qbuf);
  attn_core<<<ga, blk, 0, stream>>>(qbuf, khb, vhb, krb, seg, mg, se, rwb, rrb,
                                    rsb, avb);
  gemm_f32<true><<<gp, blk, 0, stream>>>(avb, o_w, out + SZ1);
  add_ln<<<dim3(4096), blk, 0, stream>>>(out + SZ1, g, gam, bet);
}

// Round 2
// 625.239 us; speedup vs baseline: 6.1697x; 6.1697x over previous
//
#include <hip/hip_runtime.h>
#include <math.h>

#define QS 1024
#define BSZ 4
#define NH 16
#define RL 2048

typedef __attribute__((ext_vector_type(8))) __bf16 bf16x8;
typedef __attribute__((ext_vector_type(16))) float f32x16;
typedef __attribute__((ext_vector_type(4))) float f32x4;

union BV8 { bf16x8 v; uint4 u; __bf16 e[8]; };

__device__ __forceinline__ int swz8(int row, int blk) {
  return row * 64 + ((blk ^ (row & 7)) << 3);
}

// ---------------- f32 -> bf16 convert ----------------
__global__ __launch_bounds__(256) void cvt_bf16_k(const float* __restrict__ in,
                                                  __bf16* __restrict__ out, int n) {
  int i = blockIdx.x * 1024 + threadIdx.x * 4;
  if (i + 3 < n) {
    float4 v = *(const float4*)(in + i);
    union { __bf16 b[4]; unsigned long long u; } r;
    r.b[0] = (__bf16)v.x; r.b[1] = (__bf16)v.y;
    r.b[2] = (__bf16)v.z; r.b[3] = (__bf16)v.w;
    *(unsigned long long*)(out + i) = r.u;
  }
}

// ---------------- W[k][n] f32 -> WT[n][k] bf16 ----------------
__global__ __launch_bounds__(256) void wtrans_k(const float* __restrict__ W,
                                                __bf16* __restrict__ WT) {
  __shared__ float tile[64][65];
  int k0 = blockIdx.x * 64, n0 = blockIdx.y * 64;
  int t = threadIdx.x, r = t >> 4, c4 = (t & 15) * 4;
#pragma unroll
  for (int p = 0; p < 4; ++p) {
    float4 v = *(const float4*)(W + (size_t)(k0 + r + 16 * p) * 1024 + n0 + c4);
    *(float4*)&tile[r + 16 * p][c4] = v;
  }
  __syncthreads();
#pragma unroll
  for (int p = 0; p < 4; ++p) {
    int nr = r + 16 * p;
    union { __bf16 b[4]; unsigned long long u; } o;
#pragma unroll
    for (int i = 0; i < 4; ++i) o.b[i] = (__bf16)tile[c4 + i][nr];
    *(unsigned long long*)(WT + (size_t)(n0 + nr) * 1024 + k0 + c4) = o.u;
  }
}

// ---------------- pack mask+seg into u8 [B][Q][Q] ----------------
__global__ __launch_bounds__(256) void pack_k(const float* __restrict__ mh,
                                              const float* __restrict__ mg,
                                              const float* __restrict__ seg,
                                              unsigned char* __restrict__ ph,
                                              unsigned char* __restrict__ pg) {
  size_t i = blockIdx.x;
  int j = threadIdx.x * 4;
  size_t base = i * 1024 + j;
  unsigned char oh[4][4], og[4][4];
#pragma unroll
  for (int jj = 0; jj < 4; ++jj) {
    float4 vh = *(const float4*)(mh + (base + jj) * 4);
    float4 vg = *(const float4*)(mg + (base + jj) * 4);
    float4 s0 = *(const float4*)(seg + (base + jj) * 8);
    float4 s1 = *(const float4*)(seg + (base + jj) * 8 + 4);
    float dv[4] = {s0.y, s0.w, s1.y, s1.w};
    float hv[4] = {vh.x, vh.y, vh.z, vh.w};
    float gv[4] = {vg.x, vg.y, vg.z, vg.w};
#pragma unroll
    for (int b = 0; b < 4; ++b) {
      unsigned char d = dv[b] > 0.5f ? 1 : 0;
      oh[b][jj] = d | (hv[b] > 0.5f ? 2 : 0);
      og[b][jj] = d | (gv[b] > 0.5f ? 2 : 0);
    }
  }
#pragma unroll
  for (int b = 0; b < 4; ++b) {
    *(uchar4*)(ph + ((size_t)b << 20) + base) =
        make_uchar4(oh[b][0], oh[b][1], oh[b][2], oh[b][3]);
    *(uchar4*)(pg + ((size_t)b << 20) + base) =
        make_uchar4(og[b][0], og[b][1], og[b][2], og[b][3]);
  }
}

// ---------------- bf16 MFMA GEMM: C[M][1024] = A[M][1024] * BT^T ----------------
// A row-major [M][K=1024] bf16, BT row-major [N=1024][K=1024] bf16.
template <bool OUT_BF16>
__global__ __launch_bounds__(256) void gemm_mfma(const __bf16* __restrict__ A,
                                                 const __bf16* __restrict__ BT,
                                                 void* __restrict__ Cout) {
  alignas(16) __shared__ __bf16 sA[128 * 64];
  alignas(16) __shared__ __bf16 sB[128 * 64];
  const int t = threadIdx.x;
  const int lane = t & 63, wave = t >> 6;
  const size_t m0 = (size_t)blockIdx.y * 128;
  const int n0 = blockIdx.x * 128;
  const int wm = (wave >> 1) * 64, wn = (wave & 1) * 64;

  f32x16 acc[2][2];
#pragma unroll
  for (int a = 0; a < 2; ++a)
#pragma unroll
    for (int b = 0; b < 2; ++b)
#pragma unroll
      for (int i = 0; i < 16; ++i) acc[a][b][i] = 0.f;

  for (int k0 = 0; k0 < 1024; k0 += 64) {
    __syncthreads();
#pragma unroll
    for (int p = 0; p < 4; ++p) {
      int idx = t + 256 * p;
      int row = idx >> 3, blk = idx & 7;
      uint4 va = *(const uint4*)(A + (m0 + row) * 1024 + k0 + blk * 8);
      *(uint4*)&sA[swz8(row, blk)] = va;
      uint4 vb = *(const uint4*)(BT + (size_t)(n0 + row) * 1024 + k0 + blk * 8);
      *(uint4*)&sB[swz8(row, blk)] = vb;
    }
    __syncthreads();
#pragma unroll
    for (int kk = 0; kk < 4; ++kk) {
      int blk = 2 * kk + (lane >> 5);
      bf16x8 af[2], bfr[2];
#pragma unroll
      for (int mi = 0; mi < 2; ++mi)
        af[mi] = *(bf16x8*)&sA[swz8(wm + mi * 32 + (lane & 31), blk)];
#pragma unroll
      for (int ni = 0; ni < 2; ++ni)
        bfr[ni] = *(bf16x8*)&sB[swz8(wn + ni * 32 + (lane & 31), blk)];
#pragma unroll
      for (int mi = 0; mi < 2; ++mi)
#pragma unroll
        for (int ni = 0; ni < 2; ++ni)
          acc[mi][ni] = __builtin_amdgcn_mfma_f32_32x32x16_bf16(
              af[mi], bfr[ni], acc[mi][ni], 0, 0, 0);
    }
  }
#pragma unroll
  for (int mi = 0; mi < 2; ++mi)
#pragma unroll
    for (int ni = 0; ni < 2; ++ni)
#pragma unroll
      for (int rg = 0; rg < 16; ++rg) {
        int row = wm + mi * 32 + (rg & 3) + 8 * (rg >> 2) + 4 * (lane >> 5);
        int col = wn + ni * 32 + (lane & 31);
        float v = acc[mi][ni][rg];
        if (OUT_BF16)
          ((__bf16*)Cout)[(m0 + row) * 1024 + n0 + col] = (__bf16)v;
        else
          ((float*)Cout)[(m0 + row) * 1024 + n0 + col] = v;
      }
}

// ---------------- fused relative attention, MFMA ----------------
// block: 64 q-rows, one (b,n). 32-key tiles, online softmax.
__global__ __launch_bounds__(256) void attn_mfma(
    const __bf16* __restrict__ qb, const __bf16* __restrict__ kb,
    const __bf16* __restrict__ vb, const __bf16* __restrict__ krb,
    const unsigned char* __restrict__ pk, const float* __restrict__ se,
    const float* __restrict__ rwb, const float* __restrict__ rrb,
    const float* __restrict__ rsb, __bf16* __restrict__ av) {
  const int t = threadIdx.x;
  const int lane = t & 63, wave = t >> 6;
  const int i0 = blockIdx.x * 64;
  const int n = blockIdx.y & 15, b = blockIdx.y >> 4;

  alignas(16) __shared__ __bf16 sqw[64 * 64], sqr[64 * 64];
  alignas(16) __shared__ __bf16 skh[32 * 64];
  alignas(16) __shared__ __bf16 skr[96 * 64];
  alignas(16) __shared__ __bf16 svt[64 * 32];
  alignas(16) __shared__ __bf16 sp[64 * 32];
  alignas(16) __shared__ float ss[64][36], sbd[64][36];
  alignas(16) __shared__ float sE[64][2];
  alignas(16) __shared__ float smax[64], ssum[64], sfac[64];

  // ---- init: Q tiles (+biases), E terms, running stats ----
#pragma unroll
  for (int p = 0; p < 2; ++p) {
    int idx = t + 256 * p;
    int row = idx >> 3, blk = idx & 7;
    const __bf16* src =
        qb + ((size_t)(i0 + row) * BSZ + b) * 1024 + n * 64 + blk * 8;
    BV8 raw; raw.u = *(const uint4*)src;
    BV8 qw, qr;
#pragma unroll
    for (int i = 0; i < 8; ++i) {
      float f = (float)raw.e[i];
      qw.e[i] = (__bf16)(f + rwb[n * 64 + blk * 8 + i]);
      qr.e[i] = (__bf16)(f + rrb[n * 64 + blk * 8 + i]);
    }
    *(uint4*)&sqw[swz8(row, blk)] = qw.u;
    *(uint4*)&sqr[swz8(row, blk)] = qr.u;
  }
  if (t < 128) {
    int ti = t >> 1, s = t & 1;
    const __bf16* qrow = qb + ((size_t)(i0 + ti) * BSZ + b) * 1024 + n * 64;
    const float* ev = se + (s * NH + n) * 64;
    const float* rs = rsb + n * 64;
    float e = 0.f;
    for (int d = 0; d < 64; ++d) e += ((float)qrow[d] + rs[d]) * ev[d];
    sE[ti][s] = e;
  }
  if (t < 64) { smax[t] = -INFINITY; ssum[t] = 0.f; }

  f32x16 oacc;
#pragma unroll
  for (int i = 0; i < 16; ++i) oacc[i] = 0.f;

  const int qt = wave >> 1, dt = wave & 1;
  const unsigned char* pkb = pk + ((size_t)b << 20);

  for (int jt = 0; jt < 32; ++jt) {
    const int j0 = jt * 32;
    const int w0 = j0 + 1024 - i0 - 63;
    __syncthreads();
    // ---- stage K, V^T, Kr window ----
    {
      int row = t >> 3, blk = t & 7;
      uint4 vk = *(const uint4*)(kb + ((size_t)(j0 + row) * BSZ + b) * 1024 +
                                 n * 64 + blk * 8);
      *(uint4*)&skh[swz8(row, blk)] = vk;
      int j = t >> 3, d0 = (t & 7) * 8;
      BV8 vv;
      vv.u = *(const uint4*)(vb + ((size_t)(j0 + j) * BSZ + b) * 1024 + n * 64 + d0);
#pragma unroll
      for (int i = 0; i < 8; ++i) {
        int d = d0 + i;
        svt[d * 32 + ((((j >> 3) ^ d) & 3) << 3) + (j & 7)] = vv.e[i];
      }
    }
#pragma unroll
    for (int p = 0; p < 3; ++p) {
      int idx = t + 256 * p;
      int row = idx >> 3, blk = idx & 7;
      int grow = w0 + row;
      if (grow < RL) {
        uint4 vr = *(const uint4*)(krb + ((size_t)grow * BSZ + b) * 1024 +
                                   n * 64 + blk * 8);
        *(uint4*)&skr[swz8(row, blk)] = vr;
      }
    }
    __syncthreads();

    // ---- score MFMAs ----
    if (wave < 2) {  // AC for q-half `wave`
      f32x16 acc;
#pragma unroll
      for (int i = 0; i < 16; ++i) acc[i] = 0.f;
#pragma unroll
      for (int kk = 0; kk < 4; ++kk) {
        int blk = 2 * kk + (lane >> 5);
        bf16x8 a = *(bf16x8*)&sqw[swz8(wave * 32 + (lane & 31), blk)];
        bf16x8 bb = *(bf16x8*)&skh[swz8(lane & 31, blk)];
        acc = __builtin_amdgcn_mfma_f32_32x32x16_bf16(a, bb, acc, 0, 0, 0);
      }
#pragma unroll
      for (int rg = 0; rg < 16; ++rg) {
        int row = wave * 32 + (rg & 3) + 8 * (rg >> 2) + 4 * (lane >> 5);
        ss[row][lane & 31] = acc[rg];
      }
    } else {  // BD, pre-shifted scatter into sbd
      int qtw = wave - 2;
#pragma unroll
      for (int tt = 0; tt < 2; ++tt) {
        int lt = (1 - qtw) + tt;
        f32x16 acc;
#pragma unroll
        for (int i = 0; i < 16; ++i) acc[i] = 0.f;
#pragma unroll
        for (int kk = 0; kk < 4; ++kk) {
          int blk = 2 * kk + (lane >> 5);
          bf16x8 a = *(bf16x8*)&sqr[swz8(qtw * 32 + (lane & 31), blk)];
          bf16x8 bb = *(bf16x8*)&skr[swz8(lt * 32 + (lane & 31), blk)];
          acc = __builtin_amdgcn_mfma_f32_32x32x16_bf16(a, bb, acc, 0, 0, 0);
        }
#pragma unroll
        for (int rg = 0; rg < 16; ++rg) {
          int rl = (rg & 3) + 8 * (rg >> 2) + 4 * (lane >> 5);
          int di = qtw * 32 + rl;
          int dj = lt * 32 + (lane & 31) + di - 63;
          if (dj >= 0 && dj < 32) sbd[di][dj] = acc[rg];
        }
      }
    }
    __syncthreads();

    // ---- online softmax (4 lanes per row) ----
    {
      int row = t >> 2, c0 = (t & 3) * 8;
      float e0 = sE[row][0], e1 = sE[row][1];
      unsigned long long praw =
          *(const unsigned long long*)(pkb + (size_t)(i0 + row) * 1024 + j0 + c0);
      f32x4 sa0 = *(f32x4*)&ss[row][c0], sa1 = *(f32x4*)&ss[row][c0 + 4];
      f32x4 sb0 = *(f32x4*)&sbd[row][c0], sb1 = *(f32x4*)&sbd[row][c0 + 4];
      float sc[8];
      float mx = -INFINITY;
#pragma unroll
      for (int k = 0; k < 8; ++k) {
        unsigned char pc = (praw >> (8 * k)) & 0xff;
        float base = (k < 4 ? sa0[k & 3] : sa1[k & 3]) +
                     (k < 4 ? sb0[k & 3] : sb1[k & 3]);
        float ev = (pc & 1) ? e1 : e0;
        sc[k] = (base + ev) * 0.125f - (((pc >> 1) & 1) ? 1e30f : 0.f);
        mx = fmaxf(mx, sc[k]);
      }
      mx = fmaxf(mx, __shfl_xor(mx, 1));
      mx = fmaxf(mx, __shfl_xor(mx, 2));
      float mold = smax[row];
      float mnew = fmaxf(mold, mx);
      BV8 pb;
      float psum = 0.f;
#pragma unroll
      for (int k = 0; k < 8; ++k) {
        float pv = __expf(sc[k] - mnew);
        psum += pv;
        pb.e[k] = (__bf16)pv;
      }
      *(uint4*)&sp[row * 32 + ((((c0 >> 3) ^ row) & 3) << 3)] = pb.u;
      psum += __shfl_xor(psum, 1);
      psum += __shfl_xor(psum, 2);
      if ((t & 3) == 0) {
        float f = __expf(mold - mnew);
        smax[row] = mnew;
        ssum[row] = ssum[row] * f + psum;
        sfac[row] = f;
      }
    }
    __syncthreads();

    // ---- PV: wave owns O tile (qt, dt) ----
    {
      f32x4 fv[4];
#pragma unroll
      for (int rgq = 0; rgq < 4; ++rgq)
        fv[rgq] = *(f32x4*)&sfac[qt * 32 + 8 * rgq + 4 * (lane >> 5)];
#pragma unroll
      for (int rg = 0; rg < 16; ++rg) oacc[rg] *= fv[rg >> 2][rg & 3];
#pragma unroll
      for (int step = 0; step < 2; ++step) {
        int blk = (lane >> 5) + 2 * step;
        int prow = qt * 32 + (lane & 31);
        bf16x8 a = *(bf16x8*)&sp[prow * 32 + (((blk ^ prow) & 3) << 3)];
        int drow = dt * 32 + (lane & 31);
        bf16x8 bb = *(bf16x8*)&svt[drow * 32 + (((blk ^ drow) & 3) << 3)];
        oacc = __builtin_amdgcn_mfma_f32_32x32x16_bf16(a, bb, oacc, 0, 0, 0);
      }
    }
  }

  // ---- epilogue ----
  f32x4 iv[4];
#pragma unroll
  for (int rgq = 0; rgq < 4; ++rgq)
    iv[rgq] = *(f32x4*)&ssum[qt * 32 + 8 * rgq + 4 * (lane >> 5)];
#pragma unroll
  for (int rg = 0; rg < 16; ++rg) {
    int row = qt * 32 + (rg & 3) + 8 * (rg >> 2) + 4 * (lane >> 5);
    int col = dt * 32 + (lane & 31);
    float v = oacc[rg] / iv[rg >> 2][rg & 3];
    av[((size_t)(i0 + row) * BSZ + b) * 1024 + n * 64 + col] = (__bf16)v;
  }
}

// ------------- residual add + LayerNorm (in-place on io) -------------
__global__ __launch_bounds__(256) void add_ln(float* __restrict__ io,
                                              const float* __restrict__ resid,
                                              const float* __restrict__ gam,
                                              const float* __restrict__ bet) {
  const size_t row = blockIdx.x;
  float* o = io + row * 1024;
  const float* x = resid + row * 1024;
  const int t = threadIdx.x;
  float v[4];
  float s1 = 0.f, s2 = 0.f;
#pragma unroll
  for (int k = 0; k < 4; ++k) {
    int idx = t + 256 * k;
    v[k] = o[idx] + x[idx];
    s1 += v[k];
    s2 += v[k] * v[k];
  }
#pragma unroll
  for (int off = 32; off >= 1; off >>= 1) {
    s1 += __shfl_xor(s1, off);
    s2 += __shfl_xor(s2, off);
  }
  __shared__ float r1[4], r2[4];
  if ((t & 63) == 0) { r1[t >> 6] = s1; r2[t >> 6] = s2; }
  __syncthreads();
  s1 = r1[0] + r1[1] + r1[2] + r1[3];
  s2 = r2[0] + r2[1] + r2[2] + r2[3];
  float mean = s1 * (1.f / 1024.f);
  float var = s2 * (1.f / 1024.f) - mean * mean;
  float rstd = rsqrtf(fmaxf(var, 0.f) + 1e-12f);
#pragma unroll
  for (int k = 0; k < 4; ++k) {
    int idx = t + 256 * k;
    o[idx] = (v[k] - mean) * rstd * gam[idx] + bet[idx];
  }
}

extern "C" void kernel_launch(void* const* d_in, const int* in_sizes, int n_in,
                              void* d_out, int out_size, void* d_ws,
                              size_t ws_size, hipStream_t stream) {
  const float* h = (const float*)d_in[0];
  const float* g = (const float*)d_in[1];
  const float* mh = (const float*)d_in[2];
  const float* mg = (const float*)d_in[3];
  const float* r = (const float*)d_in[4];
  const float* seg = (const float*)d_in[5];
  const float* q_w = (const float*)d_in[6];
  const float* k_w = (const float*)d_in[7];
  const float* v_w = (const float*)d_in[8];
  const float* o_w = (const float*)d_in[9];
  const float* r_w = (const float*)d_in[10];
  const float* rrb = (const float*)d_in[11];
  const float* rsb = (const float*)d_in[12];
  const float* rwb = (const float*)d_in[13];
  const float* se = (const float*)d_in[14];
  const float* gam = (const float*)d_in[15];
  const float* bet = (const float*)d_in[16];
  float* out = (float*)d_out;

  // ---- ws layout (bytes) ----
  char* w = (char*)d_ws;
  const size_t SZH = (size_t)4096 * 1024;  // elems of [Q,B,D]
  __bf16* hb = (__bf16*)w;  w += SZH * 2;
  __bf16* gb = (__bf16*)w;  w += SZH * 2;
  __bf16* rb = (__bf16*)w;  w += SZH * 4;
  __bf16* qwt = (__bf16*)w; w += (size_t)1024 * 1024 * 2;
  __bf16* kwt = (__bf16*)w; w += (size_t)1024 * 1024 * 2;
  __bf16* vwt = (__bf16*)w; w += (size_t)1024 * 1024 * 2;
  __bf16* rwt = (__bf16*)w; w += (size_t)1024 * 1024 * 2;
  __bf16* owt = (__bf16*)w; w += (size_t)1024 * 1024 * 2;
  __bf16* qpb = (__bf16*)w; w += SZH * 2;
  __bf16* khb = (__bf16*)w; w += SZH * 2;
  __bf16* vhb = (__bf16*)w; w += SZH * 2;
  __bf16* krb = (__bf16*)w; w += SZH * 4;
  __bf16* avb = (__bf16*)w; w += SZH * 2;
  unsigned char* pkh = (unsigned char*)w; w += (size_t)4 << 20;
  unsigned char* pkg = (unsigned char*)w; w += (size_t)4 << 20;

  dim3 blk(256);

  // conversions
  cvt_bf16_k<<<4096, blk, 0, stream>>>(h, hb, 4194304);
  cvt_bf16_k<<<4096, blk, 0, stream>>>(g, gb, 4194304);
  cvt_bf16_k<<<8192, blk, 0, stream>>>(r, rb, 8388608);
  cvt_bf16_k<<<1024, blk, 0, stream>>>(o_w, owt, 1048576);
  wtrans_k<<<dim3(16, 16), blk, 0, stream>>>(q_w, qwt);
  wtrans_k<<<dim3(16, 16), blk, 0, stream>>>(k_w, kwt);
  wtrans_k<<<dim3(16, 16), blk, 0, stream>>>(v_w, vwt);
  wtrans_k<<<dim3(16, 16), blk, 0, stream>>>(r_w, rwt);
  pack_k<<<1024, blk, 0, stream>>>(mh, mg, seg, pkh, pkg);

  // shared projections
  gemm_mfma<true><<<dim3(8, 32), blk, 0, stream>>>(hb, kwt, khb);
  gemm_mfma<true><<<dim3(8, 32), blk, 0, stream>>>(hb, vwt, vhb);
  gemm_mfma<true><<<dim3(8, 64), blk, 0, stream>>>(rb, rwt, krb);

  // content stream
  gemm_mfma<true><<<dim3(8, 32), blk, 0, stream>>>(hb, qwt, qpb);
  attn_mfma<<<dim3(16, 64), blk, 0, stream>>>(qpb, khb, vhb, krb, pkh, se,
                                              rwb, rrb, rsb, avb);
  gemm_mfma<false><<<dim3(8, 32), blk, 0, stream>>>(avb, owt, out);
  add_ln<<<4096, blk, 0, stream>>>(out, h, gam, bet);

  // query stream
  gemm_mfma<true><<<dim3(8, 32), blk, 0, stream>>>(gb, qwt, qpb);
  attn_mfma<<<dim3(16, 64), blk, 0, stream>>>(qpb, khb, vhb, krb, pkg, se,
                                              rwb, rrb, rsb, avb);
  gemm_mfma<false><<<dim3(8, 32), blk, 0, stream>>>(avb, owt, out + SZH);
  add_ln<<<4096, blk, 0, stream>>>(out + SZH, g, gam, bet);
}

// Round 3
// 588.728 us; speedup vs baseline: 6.5523x; 1.0620x over previous
//
#include <hip/hip_runtime.h>
#include <math.h>

#define QS 1024
#define BSZ 4
#define NH 16
#define RL 2048

typedef __attribute__((ext_vector_type(8))) __bf16 bf16x8;
typedef __attribute__((ext_vector_type(16))) float f32x16;
typedef __attribute__((ext_vector_type(4))) float f32x4;

union BV8 { bf16x8 v; uint4 u; __bf16 e[8]; };

// byte offset in a [rows][64 bf16] tile, 128B rows, slot-XOR swizzle
__device__ __forceinline__ int swzb(int row, int col8) {
  return row * 128 + (((col8 ^ row) & 7) << 4);
}
// per-wave P tile [32 q][32 key] bf16, 64B rows; key in elems
__device__ __forceinline__ int swzp(int q, int key) {
  return q * 64 + ((key * 2) ^ (((q >> 1) & 3) << 4));
}

// ---------------- f32 -> bf16 convert ----------------
__global__ __launch_bounds__(256) void cvt_bf16_k(const float* __restrict__ in,
                                                  __bf16* __restrict__ out, int n) {
  int i = blockIdx.x * 1024 + threadIdx.x * 4;
  if (i + 3 < n) {
    float4 v = *(const float4*)(in + i);
    union { __bf16 b[4]; unsigned long long u; } r;
    r.b[0] = (__bf16)v.x; r.b[1] = (__bf16)v.y;
    r.b[2] = (__bf16)v.z; r.b[3] = (__bf16)v.w;
    *(unsigned long long*)(out + i) = r.u;
  }
}

// ---------------- W[k][n] f32 -> WT[n][k] bf16 ----------------
__global__ __launch_bounds__(256) void wtrans_k(const float* __restrict__ W,
                                                __bf16* __restrict__ WT) {
  __shared__ float tile[64][65];
  int k0 = blockIdx.x * 64, n0 = blockIdx.y * 64;
  int t = threadIdx.x, r = t >> 4, c4 = (t & 15) * 4;
#pragma unroll
  for (int p = 0; p < 4; ++p) {
    float4 v = *(const float4*)(W + (size_t)(k0 + r + 16 * p) * 1024 + n0 + c4);
    *(float4*)&tile[r + 16 * p][c4] = v;
  }
  __syncthreads();
#pragma unroll
  for (int p = 0; p < 4; ++p) {
    int nr = r + 16 * p;
    union { __bf16 b[4]; unsigned long long u; } o;
#pragma unroll
    for (int i = 0; i < 4; ++i) o.b[i] = (__bf16)tile[c4 + i][nr];
    *(unsigned long long*)(WT + (size_t)(n0 + nr) * 1024 + k0 + c4) = o.u;
  }
}

// ---------------- pack mask+seg into u8 [B][Q][Q]: bit0=diff, bit1=mask ----------------
__global__ __launch_bounds__(256) void pack_k(const float* __restrict__ mh,
                                              const float* __restrict__ mg,
                                              const float* __restrict__ seg,
                                              unsigned char* __restrict__ ph,
                                              unsigned char* __restrict__ pg) {
  size_t i = blockIdx.x;
  int j = threadIdx.x * 4;
  size_t base = i * 1024 + j;
  unsigned char oh[4][4], og[4][4];
#pragma unroll
  for (int jj = 0; jj < 4; ++jj) {
    float4 vh = *(const float4*)(mh + (base + jj) * 4);
    float4 vg = *(const float4*)(mg + (base + jj) * 4);
    float4 s0 = *(const float4*)(seg + (base + jj) * 8);
    float4 s1 = *(const float4*)(seg + (base + jj) * 8 + 4);
    float dv[4] = {s0.y, s0.w, s1.y, s1.w};
    float hv[4] = {vh.x, vh.y, vh.z, vh.w};
    float gv[4] = {vg.x, vg.y, vg.z, vg.w};
#pragma unroll
    for (int b = 0; b < 4; ++b) {
      unsigned char d = dv[b] > 0.5f ? 1 : 0;
      oh[b][jj] = d | (hv[b] > 0.5f ? 2 : 0);
      og[b][jj] = d | (gv[b] > 0.5f ? 2 : 0);
    }
  }
#pragma unroll
  for (int b = 0; b < 4; ++b) {
    *(uchar4*)(ph + ((size_t)b << 20) + base) =
        make_uchar4(oh[b][0], oh[b][1], oh[b][2], oh[b][3]);
    *(uchar4*)(pg + ((size_t)b << 20) + base) =
        make_uchar4(og[b][0], og[b][1], og[b][2], og[b][3]);
  }
}

// ---------------- bf16 MFMA GEMM: C[M][1024] = A[M][1024] * BT^T ----------------
template <bool OUT_BF16>
__global__ __launch_bounds__(256) void gemm_mfma(const __bf16* __restrict__ A,
                                                 const __bf16* __restrict__ BT,
                                                 void* __restrict__ Cout) {
  alignas(16) __shared__ __bf16 sA[128 * 64];
  alignas(16) __shared__ __bf16 sB[128 * 64];
  const int t = threadIdx.x;
  const int lane = t & 63, wave = t >> 6;
  const size_t m0 = (size_t)blockIdx.y * 128;
  const int n0 = blockIdx.x * 128;
  const int wm = (wave >> 1) * 64, wn = (wave & 1) * 64;

  f32x16 acc[2][2];
#pragma unroll
  for (int a = 0; a < 2; ++a)
#pragma unroll
    for (int b = 0; b < 2; ++b)
#pragma unroll
      for (int i = 0; i < 16; ++i) acc[a][b][i] = 0.f;

  for (int k0 = 0; k0 < 1024; k0 += 64) {
    __syncthreads();
#pragma unroll
    for (int p = 0; p < 4; ++p) {
      int idx = t + 256 * p;
      int row = idx >> 3, blk = idx & 7;
      uint4 va = *(const uint4*)(A + (m0 + row) * 1024 + k0 + blk * 8);
      *(uint4*)((char*)sA + swzb(row, blk)) = va;
      uint4 vb = *(const uint4*)(BT + (size_t)(n0 + row) * 1024 + k0 + blk * 8);
      *(uint4*)((char*)sB + swzb(row, blk)) = vb;
    }
    __syncthreads();
#pragma unroll
    for (int kk = 0; kk < 4; ++kk) {
      int blk = 2 * kk + (lane >> 5);
      bf16x8 af[2], bfr[2];
#pragma unroll
      for (int mi = 0; mi < 2; ++mi)
        af[mi] = *(bf16x8*)((char*)sA + swzb(wm + mi * 32 + (lane & 31), blk));
#pragma unroll
      for (int ni = 0; ni < 2; ++ni)
        bfr[ni] = *(bf16x8*)((char*)sB + swzb(wn + ni * 32 + (lane & 31), blk));
#pragma unroll
      for (int mi = 0; mi < 2; ++mi)
#pragma unroll
        for (int ni = 0; ni < 2; ++ni)
          acc[mi][ni] = __builtin_amdgcn_mfma_f32_32x32x16_bf16(
              af[mi], bfr[ni], acc[mi][ni], 0, 0, 0);
    }
  }
#pragma unroll
  for (int mi = 0; mi < 2; ++mi)
#pragma unroll
    for (int ni = 0; ni < 2; ++ni)
#pragma unroll
      for (int rg = 0; rg < 16; ++rg) {
        int row = wm + mi * 32 + (rg & 3) + 8 * (rg >> 2) + 4 * (lane >> 5);
        int col = wn + ni * 32 + (lane & 31);
        float v = acc[mi][ni][rg];
        if (OUT_BF16)
          ((__bf16*)Cout)[(m0 + row) * 1024 + n0 + col] = (__bf16)v;
        else
          ((float*)Cout)[(m0 + row) * 1024 + n0 + col] = v;
      }
}

// ---------------- V transpose: vhb [tok][(b,n,d)] -> vtb [(b,n,d)][tok] ----------------
__global__ __launch_bounds__(256) void vtrans_k(const __bf16* __restrict__ vhb,
                                                __bf16* __restrict__ vtb) {
  alignas(16) __shared__ __bf16 st[64 * 128];  // [d][tok], 256B rows, slot=(d>>3)&7
  const int t = threadIdx.x;
  const int tok0 = blockIdx.x * 128;
  const int bn = blockIdx.y;
  const int b = bn >> 4, n = bn & 15;
#pragma unroll
  for (int p = 0; p < 4; ++p) {
    int item = t + 256 * p;
    int tok = item >> 3, c8 = item & 7;
    BV8 v;
    v.u = *(const uint4*)(vhb + ((size_t)((tok0 + tok) * 4 + b)) * 1024 + n * 64 + c8 * 8);
#pragma unroll
    for (int e = 0; e < 8; ++e) {
      int d = c8 * 8 + e;
      *(__bf16*)((char*)st + d * 256 + ((2 * tok) ^ (((d >> 3) & 7) << 4))) = v.e[e];
    }
  }
  __syncthreads();
#pragma unroll
  for (int p = 0; p < 4; ++p) {
    int item = t + 256 * p;
    int d = item >> 4, tc = (item & 15) * 8;
    uint4 v = *(uint4*)((char*)st + d * 256 + ((2 * tc) ^ (((d >> 3) & 7) << 4)));
    *(uint4*)(vtb + ((size_t)(bn * 64 + d)) * 1024 + tok0 + tc) = v;
  }
}

// ---------------- fused relative attention (per-wave key-stripes) ----------------
__global__ __launch_bounds__(256) void attn2(
    const __bf16* __restrict__ qpb, const __bf16* __restrict__ kb,
    const __bf16* __restrict__ vtb, const __bf16* __restrict__ krb,
    const unsigned char* __restrict__ pk, const float* __restrict__ se,
    const float* __restrict__ rwb, const float* __restrict__ rrb,
    const float* __restrict__ rsb, __bf16* __restrict__ av) {
  const int t = threadIdx.x;
  const int lane = t & 63, wave = t >> 6;
  const int hlf = lane >> 5, ln31 = lane & 31;
  const int qh = wave >> 1, kh = wave & 1;
  const int i0 = blockIdx.x * 64;
  const int n = blockIdx.y & 15, b = blockIdx.y >> 4;
  const int z = blockIdx.z;

  alignas(16) __shared__ __bf16 sk[64 * 64];
  alignas(16) __shared__ __bf16 sv[64 * 64];
  alignas(16) __shared__ __bf16 skr[128 * 64];
  alignas(16) __shared__ __bf16 sp[4][32 * 32];
  alignas(16) __shared__ unsigned char smask[64 * 64];
  __shared__ float2 sE[64];
  __shared__ float sl[4][32];

  const unsigned char* pkb = pk + ((size_t)z << 22) + ((size_t)b << 20);
  const int W0base = 1024 - i0 - 63;

  // ---- prologue: stage Q tile into sk + full Kr window (4 slots) ----
#pragma unroll
  for (int p = 0; p < 2; ++p) {
    int item = t + 256 * p;
    int row = item >> 3, c8 = item & 7;
    *(uint4*)((char*)sk + swzb(row, c8)) =
        *(const uint4*)(qpb + ((size_t)((z * 1024 + i0 + row) * 4 + b)) * 1024 +
                        n * 64 + c8 * 8);
  }
#pragma unroll
  for (int p = 0; p < 4; ++p) {
    int item = t + 256 * p;
    int row = item >> 3, c8 = item & 7;
    int grow = W0base + row;  // in [1, 1151]
    *(uint4*)((char*)skr + swzb(row, c8)) =
        *(const uint4*)(krb + ((size_t)(grow * 4 + b)) * 1024 + n * 64 + c8 * 8);
  }
  __syncthreads();

  // ---- Q fragments (+biases) and segment-E partial dots ----
  bf16x8 qw[4], qr[4];
  float e0p = 0.f, e1p = 0.f;
#pragma unroll
  for (int kk = 0; kk < 4; ++kk) {
    BV8 raw;
    raw.u = *(uint4*)((char*)sk + swzb(32 * qh + ln31, 2 * kk + hlf));
    int d0 = 16 * kk + 8 * hlf;
    float4 w0 = *(const float4*)(rwb + n * 64 + d0);
    float4 w1 = *(const float4*)(rwb + n * 64 + d0 + 4);
    float4 r0 = *(const float4*)(rrb + n * 64 + d0);
    float4 r1 = *(const float4*)(rrb + n * 64 + d0 + 4);
    float4 sb0 = *(const float4*)(rsb + n * 64 + d0);
    float4 sb1 = *(const float4*)(rsb + n * 64 + d0 + 4);
    float4 ea0 = *(const float4*)(se + n * 64 + d0);
    float4 ea1 = *(const float4*)(se + n * 64 + d0 + 4);
    float4 eb0 = *(const float4*)(se + 1024 + n * 64 + d0);
    float4 eb1 = *(const float4*)(se + 1024 + n * 64 + d0 + 4);
    float wv[8] = {w0.x, w0.y, w0.z, w0.w, w1.x, w1.y, w1.z, w1.w};
    float rv[8] = {r0.x, r0.y, r0.z, r0.w, r1.x, r1.y, r1.z, r1.w};
    float sv_[8] = {sb0.x, sb0.y, sb0.z, sb0.w, sb1.x, sb1.y, sb1.z, sb1.w};
    float ev0[8] = {ea0.x, ea0.y, ea0.z, ea0.w, ea1.x, ea1.y, ea1.z, ea1.w};
    float ev1[8] = {eb0.x, eb0.y, eb0.z, eb0.w, eb1.x, eb1.y, eb1.z, eb1.w};
    BV8 qwv, qrv;
#pragma unroll
    for (int i = 0; i < 8; ++i) {
      float f = (float)raw.e[i];
      qwv.e[i] = (__bf16)(f + wv[i]);
      qrv.e[i] = (__bf16)(f + rv[i]);
      float fs = f + sv_[i];
      e0p += fs * ev0[i];
      e1p += fs * ev1[i];
    }
    qw[kk] = qwv.v;
    qr[kk] = qrv.v;
  }
  e0p += __shfl_xor(e0p, 32);
  e1p += __shfl_xor(e1p, 32);
  if (lane < 32) sE[32 * qh + lane] = make_float2(e0p, e1p);

  f32x16 oacc0, oacc1;
#pragma unroll
  for (int i = 0; i < 16; ++i) { oacc0[i] = 0.f; oacc1[i] = 0.f; }
  float lsum = 0.f;
  char* spw = (char*)sp[wave];
  const int base = 1 + kh - qh;

  for (int jt = 0; jt < 16; ++jt) {
    const int J0 = jt * 64;
    __syncthreads();  // previous compute (and prologue frag reads) done
    // ---- stage K, V^T, mask, next Kr (ring) ----
#pragma unroll
    for (int p = 0; p < 2; ++p) {
      int item = t + 256 * p;
      int row = item >> 3, c8 = item & 7;
      *(uint4*)((char*)sk + swzb(row, c8)) =
          *(const uint4*)(kb + ((size_t)((J0 + row) * 4 + b)) * 1024 + n * 64 + c8 * 8);
      *(uint4*)((char*)sv + swzb(row, c8)) =
          *(const uint4*)(vtb + ((size_t)((b * 16 + n) * 64 + row)) * 1024 + J0 + c8 * 8);
    }
    {
      int row = t >> 2, c16 = (t & 3) * 16;
      *(uint4*)(smask + row * 64 + c16) =
          *(const uint4*)(pkb + (size_t)(i0 + row) * 1024 + J0 + c16);
    }
    if (jt < 15) {
#pragma unroll
      for (int p = 0; p < 2; ++p) {
        int item = t + 256 * p;
        int r64 = item >> 3, c8 = item & 7;
        int grow = min(W0base + J0 + 128 + r64, 2047);
        int slot = (2 * jt + (r64 >> 5)) & 3;
        *(uint4*)((char*)skr + swzb(slot * 32 + (r64 & 31), c8)) =
            *(const uint4*)(krb + ((size_t)(grow * 4 + b)) * 1024 + n * 64 + c8 * 8);
      }
    }
    __syncthreads();

    // ---- AC: D[q'][key'] over wave's 32-key stripe ----
    f32x16 ac;
#pragma unroll
    for (int i = 0; i < 16; ++i) ac[i] = 0.f;
#pragma unroll
    for (int kk = 0; kk < 4; ++kk) {
      bf16x8 bb = *(bf16x8*)((char*)sk + swzb(32 * kh + ln31, 2 * kk + hlf));
      ac = __builtin_amdgcn_mfma_f32_32x32x16_bf16(qw[kk], bb, ac, 0, 0, 0);
    }
    // ---- BD: two window tiles ----
    f32x16 bd0, bd1;
#pragma unroll
    for (int i = 0; i < 16; ++i) { bd0[i] = 0.f; bd1[i] = 0.f; }
    const int slot0 = (2 * jt + base) & 3, slot1 = (2 * jt + base + 1) & 3;
#pragma unroll
    for (int kk = 0; kk < 4; ++kk) {
      bf16x8 b0 = *(bf16x8*)((char*)skr + swzb(slot0 * 32 + ln31, 2 * kk + hlf));
      bd0 = __builtin_amdgcn_mfma_f32_32x32x16_bf16(qr[kk], b0, bd0, 0, 0, 0);
      bf16x8 b1 = *(bf16x8*)((char*)skr + swzb(slot1 * 32 + ln31, 2 * kk + hlf));
      bd1 = __builtin_amdgcn_mfma_f32_32x32x16_bf16(qr[kk], b1, bd1, 0, 0, 0);
    }
    // ---- realign BD (per-row rotation), score, exp, write P ----
#pragma unroll
    for (int rg = 0; rg < 16; ++rg) {
      int q_ = (rg & 3) + 8 * (rg >> 2) + 4 * hlf;
      int src = ((lane & 32) | ((ln31 + 31 - q_) & 31)) << 2;
      float bv0 = __int_as_float(
          __builtin_amdgcn_ds_bpermute(src, __float_as_int(bd0[rg])));
      float bv1 = __int_as_float(
          __builtin_amdgcn_ds_bpermute(src, __float_as_int(bd1[rg])));
      float bd = (ln31 > q_) ? bv1 : bv0;
      int qq = 32 * qh + q_;
      float2 ev = sE[qq];
      unsigned char mb = smask[qq * 64 + 32 * kh + ln31];
      float e = (mb & 1) ? ev.y : ev.x;
      float s = (ac[rg] + bd + e) * 0.18033688f;  // 0.125 * log2(e)
      float p = (mb & 2) ? 0.f : exp2f(s);
      *(__bf16*)(spw + swzp(q_, ln31)) = (__bf16)p;
    }
    // ---- lsum: in-lane row-sum of wave's P stripe ----
    {
      BV8 pa, pb;
      pa.u = *(uint4*)(spw + swzp(ln31, 16 * hlf));
      pb.u = *(uint4*)(spw + swzp(ln31, 16 * hlf + 8));
      float srow = 0.f;
#pragma unroll
      for (int i = 0; i < 8; ++i) srow += (float)pa.e[i] + (float)pb.e[i];
      srow += __shfl_xor(srow, 32);
      lsum += srow;
    }
    // ---- PV ----
#pragma unroll
    for (int kk = 0; kk < 2; ++kk) {
      bf16x8 a = *(bf16x8*)(spw + swzp(ln31, 16 * kk + 8 * hlf));
      bf16x8 v0 = *(bf16x8*)((char*)sv + swzb(ln31, 4 * kh + 2 * kk + hlf));
      oacc0 = __builtin_amdgcn_mfma_f32_32x32x16_bf16(a, v0, oacc0, 0, 0, 0);
      bf16x8 v1 = *(bf16x8*)((char*)sv + swzb(32 + ln31, 4 * kh + 2 * kk + hlf));
      oacc1 = __builtin_amdgcn_mfma_f32_32x32x16_bf16(a, v1, oacc1, 0, 0, 0);
    }
  }

  // ---- epilogue: merge kh-pairs, divide by l, store ----
  __syncthreads();
  sl[wave][ln31] = lsum;
  if (kh == 1) {
#pragma unroll
    for (int r4 = 0; r4 < 4; ++r4) {
      f32x4 v0 = {oacc0[4 * r4], oacc0[4 * r4 + 1], oacc0[4 * r4 + 2], oacc0[4 * r4 + 3]};
      *(f32x4*)((char*)skr + qh * 8192 + swzb(lane, r4)) = v0;
      f32x4 v1 = {oacc1[4 * r4], oacc1[4 * r4 + 1], oacc1[4 * r4 + 2], oacc1[4 * r4 + 3]};
      *(f32x4*)((char*)skr + qh * 8192 + swzb(lane, 4 + r4)) = v1;
    }
  }
  __syncthreads();
  if (kh == 0) {
#pragma unroll
    for (int r4 = 0; r4 < 4; ++r4) {
      f32x4 v0 = *(f32x4*)((char*)skr + qh * 8192 + swzb(lane, r4));
      f32x4 v1 = *(f32x4*)((char*)skr + qh * 8192 + swzb(lane, 4 + r4));
#pragma unroll
      for (int i = 0; i < 4; ++i) {
        oacc0[4 * r4 + i] += v0[i];
        oacc1[4 * r4 + i] += v1[i];
      }
    }
#pragma unroll
    for (int rg = 0; rg < 16; ++rg) {
      int q_ = (rg & 3) + 8 * (rg >> 2) + 4 * hlf;
      float l = sl[2 * qh][q_] + sl[2 * qh + 1][q_];
      float rl = __fdividef(1.f, l);
      size_t orow =
          ((size_t)((z * 1024 + i0 + 32 * qh + q_) * 4 + b)) * 1024 + n * 64;
      av[orow + ln31] = (__bf16)(oacc0[rg] * rl);
      av[orow + 32 + ln31] = (__bf16)(oacc1[rg] * rl);
    }
  }
}

// ------------- residual add + LayerNorm (in-place on io) -------------
__global__ __launch_bounds__(256) void add_ln(float* __restrict__ io,
                                              const float* __restrict__ h,
                                              const float* __restrict__ g,
                                              const float* __restrict__ gam,
                                              const float* __restrict__ bet) {
  const size_t row = blockIdx.x;
  float* o = io + row * 1024;
  const float* x = (row < 4096) ? (h + row * 1024) : (g + (row - 4096) * 1024);
  const int t = threadIdx.x;
  float v[4];
  float s1 = 0.f, s2 = 0.f;
#pragma unroll
  for (int k = 0; k < 4; ++k) {
    int idx = t + 256 * k;
    v[k] = o[idx] + x[idx];
    s1 += v[k];
    s2 += v[k] * v[k];
  }
#pragma unroll
  for (int off = 32; off >= 1; off >>= 1) {
    s1 += __shfl_xor(s1, off);
    s2 += __shfl_xor(s2, off);
  }
  __shared__ float r1[4], r2[4];
  if ((t & 63) == 0) { r1[t >> 6] = s1; r2[t >> 6] = s2; }
  __syncthreads();
  s1 = r1[0] + r1[1] + r1[2] + r1[3];
  s2 = r2[0] + r2[1] + r2[2] + r2[3];
  float mean = s1 * (1.f / 1024.f);
  float var = s2 * (1.f / 1024.f) - mean * mean;
  float rstd = rsqrtf(fmaxf(var, 0.f) + 1e-12f);
#pragma unroll
  for (int k = 0; k < 4; ++k) {
    int idx = t + 256 * k;
    o[idx] = (v[k] - mean) * rstd * gam[idx] + bet[idx];
  }
}

extern "C" void kernel_launch(void* const* d_in, const int* in_sizes, int n_in,
                              void* d_out, int out_size, void* d_ws,
                              size_t ws_size, hipStream_t stream) {
  const float* h = (const float*)d_in[0];
  const float* g = (const float*)d_in[1];
  const float* mh = (const float*)d_in[2];
  const float* mg = (const float*)d_in[3];
  const float* r = (const float*)d_in[4];
  const float* seg = (const float*)d_in[5];
  const float* q_w = (const float*)d_in[6];
  const float* k_w = (const float*)d_in[7];
  const float* v_w = (const float*)d_in[8];
  const float* o_w = (const float*)d_in[9];
  const float* r_w = (const float*)d_in[10];
  const float* rrb = (const float*)d_in[11];
  const float* rsb = (const float*)d_in[12];
  const float* rwb = (const float*)d_in[13];
  const float* se = (const float*)d_in[14];
  const float* gam = (const float*)d_in[15];
  const float* bet = (const float*)d_in[16];
  float* out = (float*)d_out;

  // ---- ws layout ----
  char* w = (char*)d_ws;
  __bf16* hgb = (__bf16*)w;                    // 16MB, [8192][1024]
  __bf16* vtb = (__bf16*)w;                    // aliases hgb (dead after q-GEMM)
  w += (size_t)16 << 20;
  __bf16* rb = (__bf16*)w;                     // 16MB
  __bf16* avb = (__bf16*)w;                    // aliases rb (dead after r-GEMM)
  w += (size_t)16 << 20;
  __bf16* qwt = (__bf16*)w; w += (size_t)2 << 20;
  __bf16* kwt = (__bf16*)w; w += (size_t)2 << 20;
  __bf16* vwt = (__bf16*)w; w += (size_t)2 << 20;
  __bf16* rwt = (__bf16*)w; w += (size_t)2 << 20;
  __bf16* owt = (__bf16*)w; w += (size_t)2 << 20;
  __bf16* qpb = (__bf16*)w; w += (size_t)16 << 20;   // [8192][1024]
  __bf16* khb = (__bf16*)w; w += (size_t)8 << 20;
  __bf16* vhb = (__bf16*)w; w += (size_t)8 << 20;
  __bf16* krb = (__bf16*)w; w += (size_t)16 << 20;
  unsigned char* pkh = (unsigned char*)w; w += (size_t)4 << 20;
  unsigned char* pkg = (unsigned char*)w; w += (size_t)4 << 20;

  dim3 blk(256);

  cvt_bf16_k<<<4096, blk, 0, stream>>>(h, hgb, 4194304);
  cvt_bf16_k<<<4096, blk, 0, stream>>>(g, hgb + 4194304, 4194304);
  cvt_bf16_k<<<8192, blk, 0, stream>>>(r, rb, 8388608);
  cvt_bf16_k<<<1024, blk, 0, stream>>>(o_w, owt, 1048576);
  wtrans_k<<<dim3(16, 16), blk, 0, stream>>>(q_w, qwt);
  wtrans_k<<<dim3(16, 16), blk, 0, stream>>>(k_w, kwt);
  wtrans_k<<<dim3(16, 16), blk, 0, stream>>>(v_w, vwt);
  wtrans_k<<<dim3(16, 16), blk, 0, stream>>>(r_w, rwt);
  pack_k<<<1024, blk, 0, stream>>>(mh, mg, seg, pkh, pkg);

  gemm_mfma<true><<<dim3(8, 32), blk, 0, stream>>>(hgb, kwt, khb);
  gemm_mfma<true><<<dim3(8, 32), blk, 0, stream>>>(hgb, vwt, vhb);
  gemm_mfma<true><<<dim3(8, 64), blk, 0, stream>>>(rb, rwt, krb);
  gemm_mfma<true><<<dim3(8, 64), blk, 0, stream>>>(hgb, qwt, qpb);  // hgb dead after
  vtrans_k<<<dim3(8, 64), blk, 0, stream>>>(vhb, vtb);

  attn2<<<dim3(16, 64, 2), blk, 0, stream>>>(qpb, khb, vtb, krb, pkh, se, rwb,
                                             rrb, rsb, avb);

  gemm_mfma<false><<<dim3(8, 64), blk, 0, stream>>>(avb, owt, out);
  add_ln<<<8192, blk, 0, stream>>>(out, h, g, gam, bet);
}

// Round 4
// 528.178 us; speedup vs baseline: 7.3034x; 1.1146x over previous
//
#include <hip/hip_runtime.h>
#include <math.h>

#define QS 1024
#define BSZ 4
#define NH 16
#define RL 2048

typedef __attribute__((ext_vector_type(8))) __bf16 bf16x8;
typedef __attribute__((ext_vector_type(16))) float f32x16;
typedef __attribute__((ext_vector_type(4))) float f32x4;

union BV8 { bf16x8 v; uint4 u; __bf16 e[8]; unsigned w[4]; };

// byte offset in a [rows][64 bf16] tile, 128B rows, blk-XOR swizzle
__device__ __forceinline__ int swzb(int row, int blk) {
  return row * 128 + (((blk ^ row) & 7) << 4);
}

typedef __attribute__((address_space(3))) unsigned int lds_u32;
typedef __attribute__((address_space(1))) const unsigned int glb_u32;
__device__ __forceinline__ void gld16(const void* g, void* l) {
  __builtin_amdgcn_global_load_lds((glb_u32*)g, (lds_u32*)l, 16, 0, 0);
}

// ---------------- f32 -> bf16 convert ----------------
__global__ __launch_bounds__(256) void cvt_bf16_k(const float* __restrict__ in,
                                                  __bf16* __restrict__ out, int n) {
  int i = blockIdx.x * 1024 + threadIdx.x * 4;
  if (i + 3 < n) {
    float4 v = *(const float4*)(in + i);
    union { __bf16 b[4]; unsigned long long u; } r;
    r.b[0] = (__bf16)v.x; r.b[1] = (__bf16)v.y;
    r.b[2] = (__bf16)v.z; r.b[3] = (__bf16)v.w;
    *(unsigned long long*)(out + i) = r.u;
  }
}

// ---------------- W[k][n] f32 -> WT[n][k] bf16 ----------------
__global__ __launch_bounds__(256) void wtrans_k(const float* __restrict__ W,
                                                __bf16* __restrict__ WT) {
  __shared__ float tile[64][65];
  int k0 = blockIdx.x * 64, n0 = blockIdx.y * 64;
  int t = threadIdx.x, r = t >> 4, c4 = (t & 15) * 4;
#pragma unroll
  for (int p = 0; p < 4; ++p) {
    float4 v = *(const float4*)(W + (size_t)(k0 + r + 16 * p) * 1024 + n0 + c4);
    *(float4*)&tile[r + 16 * p][c4] = v;
  }
  __syncthreads();
#pragma unroll
  for (int p = 0; p < 4; ++p) {
    int nr = r + 16 * p;
    union { __bf16 b[4]; unsigned long long u; } o;
#pragma unroll
    for (int i = 0; i < 4; ++i) o.b[i] = (__bf16)tile[c4 + i][nr];
    *(unsigned long long*)(WT + (size_t)(n0 + nr) * 1024 + k0 + c4) = o.u;
  }
}

// ------- pack masks to bitfields: mbits[tn(z)][b][j][1024 i-bits] -------
__global__ __launch_bounds__(256) void packbits_k(const float* __restrict__ mh,
                                                  const float* __restrict__ mg,
                                                  unsigned int* __restrict__ mbits) {
  __shared__ unsigned char nib[2][16][64];
  const int t = threadIdx.x;
  const int i0b = blockIdx.x * 64;
  const int jb0 = blockIdx.y * 64;
  const float* srcs[2] = {mh, mg};
#pragma unroll
  for (int tn = 0; tn < 2; ++tn) {
    const float* in = srcs[tn];
#pragma unroll
    for (int p = 0; p < 4; ++p) {
      int item = t + 256 * p;
      int iloc = item >> 4, jbq = item & 15;
      float4 v = *(const float4*)(in + (size_t)(i0b + iloc) * 4096 + jb0 + jbq * 4);
      unsigned char nb = (v.x > 0.5f ? 1 : 0) | (v.y > 0.5f ? 2 : 0) |
                         (v.z > 0.5f ? 4 : 0) | (v.w > 0.5f ? 8 : 0);
      nib[tn][jbq][iloc] = nb;
    }
  }
  __syncthreads();
  {
    int tn = t >> 7, rem = t & 127;
    int jbl = rem >> 1, dw = rem & 1;
    int jbq = jbl >> 2, e = jbl & 3;
    uint4 u0 = *(uint4*)&nib[tn][jbq][32 * dw];
    uint4 u1 = *(uint4*)&nib[tn][jbq][32 * dw + 16];
    unsigned d[8] = {u0.x, u0.y, u0.z, u0.w, u1.x, u1.y, u1.z, u1.w};
    unsigned out = 0;
#pragma unroll
    for (int c = 0; c < 8; ++c) {
      unsigned bits = (d[c] >> e) & 0x01010101u;
      unsigned nv = ((bits * 0x01020408u) >> 24) & 0xFu;
      out |= nv << (4 * c);
    }
    int jb = jb0 + jbl;
    int b = jb & 3, j = jb >> 2;
    mbits[(size_t)(((tn * 4 + b) * 1024 + j)) * 32 + (i0b >> 5) + dw] = out;
  }
}

// ------- segv[b][j] = seg-bit of token j (relative to token 0) -------
__global__ __launch_bounds__(256) void segv_k(const float* __restrict__ seg,
                                              unsigned char* __restrict__ segv) {
  int id = blockIdx.x * 256 + threadIdx.x;
  if (id < 4096) {
    int b = id >> 10, j = id & 1023;
    segv[b * 1024 + j] = (seg[(size_t)(j * 4 + b) * 2 + 1] > 0.5f) ? 1 : 0;
  }
}

// ---------------- bf16 MFMA GEMM: C[M][1024] = A[M][1024] * BT^T ----------------
template <bool OUT_BF16>
__global__ __launch_bounds__(256) void gemm_mfma(const __bf16* __restrict__ A,
                                                 const __bf16* __restrict__ BT,
                                                 void* __restrict__ Cout) {
  alignas(16) __shared__ __bf16 sA[128 * 64];
  alignas(16) __shared__ __bf16 sB[128 * 64];
  const int t = threadIdx.x;
  const int lane = t & 63, wave = t >> 6;
  const size_t m0 = (size_t)blockIdx.y * 128;
  const int n0 = blockIdx.x * 128;
  const int wm = (wave >> 1) * 64, wn = (wave & 1) * 64;

  f32x16 acc[2][2];
#pragma unroll
  for (int a = 0; a < 2; ++a)
#pragma unroll
    for (int b = 0; b < 2; ++b)
#pragma unroll
      for (int i = 0; i < 16; ++i) acc[a][b][i] = 0.f;

  for (int k0 = 0; k0 < 1024; k0 += 64) {
    __syncthreads();
#pragma unroll
    for (int p = 0; p < 4; ++p) {
      int idx = t + 256 * p;
      int row = idx >> 3, blk = idx & 7;
      int sblk = (blk ^ (row & 7)) * 8;
      gld16(A + (m0 + row) * 1024 + k0 + sblk, (char*)sA + idx * 16);
      gld16(BT + (size_t)(n0 + row) * 1024 + k0 + sblk, (char*)sB + idx * 16);
    }
    __syncthreads();
#pragma unroll
    for (int kk = 0; kk < 4; ++kk) {
      int blk = 2 * kk + (lane >> 5);
      bf16x8 af[2], bfr[2];
#pragma unroll
      for (int mi = 0; mi < 2; ++mi)
        af[mi] = *(bf16x8*)((char*)sA + swzb(wm + mi * 32 + (lane & 31), blk));
#pragma unroll
      for (int ni = 0; ni < 2; ++ni)
        bfr[ni] = *(bf16x8*)((char*)sB + swzb(wn + ni * 32 + (lane & 31), blk));
#pragma unroll
      for (int mi = 0; mi < 2; ++mi)
#pragma unroll
        for (int ni = 0; ni < 2; ++ni)
          acc[mi][ni] = __builtin_amdgcn_mfma_f32_32x32x16_bf16(
              af[mi], bfr[ni], acc[mi][ni], 0, 0, 0);
    }
  }
#pragma unroll
  for (int mi = 0; mi < 2; ++mi)
#pragma unroll
    for (int ni = 0; ni < 2; ++ni)
#pragma unroll
      for (int rg = 0; rg < 16; ++rg) {
        int row = wm + mi * 32 + (rg & 3) + 8 * (rg >> 2) + 4 * (lane >> 5);
        int col = wn + ni * 32 + (lane & 31);
        float v = acc[mi][ni][rg];
        if (OUT_BF16)
          ((__bf16*)Cout)[(m0 + row) * 1024 + n0 + col] = (__bf16)v;
        else
          ((float*)Cout)[(m0 + row) * 1024 + n0 + col] = v;
      }
}

// ---------------- V transpose: vhb [tok][(b,n,d)] -> vtb [(b,n,d)][tok] ----------------
__global__ __launch_bounds__(256) void vtrans_k(const __bf16* __restrict__ vhb,
                                                __bf16* __restrict__ vtb) {
  alignas(16) __shared__ __bf16 st[64 * 128];
  const int t = threadIdx.x;
  const int tok0 = blockIdx.x * 128;
  const int bn = blockIdx.y;
  const int b = bn >> 4, n = bn & 15;
#pragma unroll
  for (int p = 0; p < 4; ++p) {
    int item = t + 256 * p;
    int tok = item >> 3, c8 = item & 7;
    BV8 v;
    v.u = *(const uint4*)(vhb + ((size_t)((tok0 + tok) * 4 + b)) * 1024 + n * 64 + c8 * 8);
#pragma unroll
    for (int e = 0; e < 8; ++e) {
      int d = c8 * 8 + e;
      *(__bf16*)((char*)st + d * 256 + ((2 * tok) ^ (((d >> 3) & 7) << 4))) = v.e[e];
    }
  }
  __syncthreads();
#pragma unroll
  for (int p = 0; p < 4; ++p) {
    int item = t + 256 * p;
    int d = item >> 4, tc = (item & 15) * 8;
    uint4 v = *(uint4*)((char*)st + d * 256 + ((2 * tc) ^ (((d >> 3) & 7) << 4)));
    *(uint4*)(vtb + ((size_t)(bn * 64 + d)) * 1024 + tok0 + tc) = v;
  }
}

// ---------------- fused relative attention v3 ----------------
__global__ __launch_bounds__(256, 3) void attn3(
    const __bf16* __restrict__ qpb, const __bf16* __restrict__ kb,
    const __bf16* __restrict__ vtb, const __bf16* __restrict__ krb,
    const unsigned int* __restrict__ mbits, const unsigned char* __restrict__ segv,
    const float* __restrict__ se, const float* __restrict__ rwb,
    const float* __restrict__ rrb, const float* __restrict__ rsb,
    __bf16* __restrict__ av) {
  const int t = threadIdx.x;
  const int lane = t & 63, wave = t >> 6;
  const int hlf = lane >> 5, ln31 = lane & 31;
  const int qh = wave >> 1, kh = wave & 1;  // kh doubles as d-tile in PV

  // XCD-aware 1D decode: 8 heads of one batch per XCD
  const int bid = blockIdx.x;
  const int xcd = bid & 7, idx0 = bid >> 3;
  const int bn = xcd * 8 + (idx0 & 7);
  const int i0 = ((idx0 >> 3) & 15) * 64;
  const int z = idx0 >> 7;
  const int b = bn >> 4, n = bn & 15;

  alignas(16) __shared__ __bf16 ring[8 * 32 * 64];  // 32KB Kr sliding window
  alignas(16) __shared__ __bf16 sp[2][32 * 64];     // 8KB P (per q-half)
  __shared__ float sl[4][2][16];

  const int wpro = 960 - i0;  // ring prologue base (>=0, mult of 32)
  // ---- prologue: stage ring rows [wpro, wpro+127] ----
#pragma unroll
  for (int p = 0; p < 4; ++p) {
    int item = t + 256 * p;
    int wl = item >> 3, blk = item & 7;
    int w = wpro + wl;
    int wc = min(w, 2047);
    gld16(krb + ((size_t)(wc * 4 + b)) * 1024 + n * 64 + ((blk ^ (w & 7)) << 3),
          (char*)ring + ((w >> 5) & 7) * 4096 + (w & 31) * 128 + blk * 16);
  }

  // ---- Q fragments (+biases), alpha/beta for segment fold ----
  const size_t qbase =
      ((size_t)((z * 1024 + i0 + 32 * qh + ln31) * 4 + b)) * 1024 + n * 64;
  bf16x8 qw[4], qr[4];
  float e0 = 0.f, e1 = 0.f;
#pragma unroll
  for (int kk = 0; kk < 4; ++kk) {
    BV8 raw;
    raw.u = *(const uint4*)(qpb + qbase + 16 * kk + 8 * hlf);
    int d0 = 16 * kk + 8 * hlf;
    float4 w0 = *(const float4*)(rwb + n * 64 + d0);
    float4 w1 = *(const float4*)(rwb + n * 64 + d0 + 4);
    float4 r0 = *(const float4*)(rrb + n * 64 + d0);
    float4 r1 = *(const float4*)(rrb + n * 64 + d0 + 4);
    float4 sb0 = *(const float4*)(rsb + n * 64 + d0);
    float4 sb1 = *(const float4*)(rsb + n * 64 + d0 + 4);
    float4 ea0 = *(const float4*)(se + n * 64 + d0);
    float4 ea1 = *(const float4*)(se + n * 64 + d0 + 4);
    float4 eb0 = *(const float4*)(se + 1024 + n * 64 + d0);
    float4 eb1 = *(const float4*)(se + 1024 + n * 64 + d0 + 4);
    float wv[8] = {w0.x, w0.y, w0.z, w0.w, w1.x, w1.y, w1.z, w1.w};
    float rv[8] = {r0.x, r0.y, r0.z, r0.w, r1.x, r1.y, r1.z, r1.w};
    float sv_[8] = {sb0.x, sb0.y, sb0.z, sb0.w, sb1.x, sb1.y, sb1.z, sb1.w};
    float ev0[8] = {ea0.x, ea0.y, ea0.z, ea0.w, ea1.x, ea1.y, ea1.z, ea1.w};
    float ev1[8] = {eb0.x, eb0.y, eb0.z, eb0.w, eb1.x, eb1.y, eb1.z, eb1.w};
    BV8 qwv, qrv;
#pragma unroll
    for (int i = 0; i < 8; ++i) {
      float f = (float)raw.e[i];
      qwv.e[i] = (__bf16)(f + wv[i]);
      qrv.e[i] = (__bf16)(f + rv[i]);
      float fs = f + sv_[i];
      e0 += fs * ev0[i];
      e1 += fs * ev1[i];
    }
    qw[kk] = qwv.v;
    qr[kk] = qrv.v;
  }
  e0 += __shfl_xor(e0, 32);
  e1 += __shfl_xor(e1, 32);
  float si = (float)segv[b * 1024 + i0 + 32 * qh + ln31];
  float alpha = e0 + (e1 - e0) * si;
  float beta = (e1 - e0) * (1.f - 2.f * si);
  bf16x8 augA;
  {
    BV8 aa;
    aa.w[0] = aa.w[1] = aa.w[2] = aa.w[3] = 0;
    if (!hlf) {
      union { __bf16 b2[2]; unsigned u; } w2;
      w2.b2[0] = (__bf16)alpha;
      w2.b2[1] = (__bf16)beta;
      aa.w[0] = w2.u;
    }
    augA = aa.v;
  }

  f32x16 oacc, colsum;
#pragma unroll
  for (int i = 0; i < 16; ++i) { oacc[i] = 0.f; colsum[i] = 0.f; }

  __syncthreads();  // prologue ring visible

  char* spw = (char*)sp[qh];
  const unsigned char* segp = segv + b * 1024;

  for (int jt = 0; jt < 16; ++jt) {
    const int J0 = 64 * jt;
    // ---- stage next 2 ring slots (read at jt+1; disjoint from jt's 4) ----
    {
      int wsb = wpro + 128 + 64 * jt;
#pragma unroll
      for (int p = 0; p < 2; ++p) {
        int item = t + 256 * p;
        int wl = item >> 3, blk = item & 7;
        int w = wsb + wl;
        int wc = min(w, 2047);
        gld16(krb + ((size_t)(wc * 4 + b)) * 1024 + n * 64 + ((blk ^ (w & 7)) << 3),
              (char*)ring + ((w >> 5) & 7) * 4096 + (w & 31) * 128 + blk * 16);
      }
    }
    // ---- K frags, mask dword, seg byte (global, L2-hit) ----
    const __bf16* kp =
        kb + ((size_t)((J0 + 32 * kh + ln31) * 4 + b)) * 1024 + n * 64 + 8 * hlf;
    bf16x8 kf[4];
    kf[0] = *(const bf16x8*)(kp);
    kf[1] = *(const bf16x8*)(kp + 16);
    kf[2] = *(const bf16x8*)(kp + 32);
    kf[3] = *(const bf16x8*)(kp + 48);
    unsigned praw =
        mbits[(size_t)((z * 4 + b) * 1024 + J0 + 32 * kh + ln31) * 32 + (i0 >> 5) + qh];
    praw >>= (hlf * 4);
    unsigned sj = segp[J0 + 32 * kh + ln31];
    bf16x8 augB;
    {
      BV8 bb2;
      bb2.w[0] = hlf ? 0u : (0x3F80u | (sj * 0x3F800000u));
      bb2.w[1] = bb2.w[2] = bb2.w[3] = 0;
      augB = bb2.v;
    }

    // ---- BD: two window tiles from ring ----
    const int base0 = J0 + 32 * (kh - qh) + 993 - i0;
    f32x16 bd[2];
#pragma unroll
    for (int tt = 0; tt < 2; ++tt) {
#pragma unroll
      for (int i = 0; i < 16; ++i) bd[tt][i] = 0.f;
      int w = base0 + 32 * tt + ln31;
      int rbyte = ((w >> 5) & 7) * 4096 + (w & 31) * 128;
      int wx = (w & 7) << 4;
#pragma unroll
      for (int kk = 0; kk < 4; ++kk) {
        bf16x8 bbr = *(const bf16x8*)((char*)ring + rbyte + (((2 * kk + hlf) << 4) ^ wx));
        bd[tt] = __builtin_amdgcn_mfma_f32_32x32x16_bf16(qr[kk], bbr, bd[tt], 0, 0, 0);
      }
    }
    // ---- AC (+ segment fold) ----
    f32x16 ac;
#pragma unroll
    for (int i = 0; i < 16; ++i) ac[i] = 0.f;
#pragma unroll
    for (int kk = 0; kk < 4; ++kk)
      ac = __builtin_amdgcn_mfma_f32_32x32x16_bf16(qw[kk], kf[kk], ac, 0, 0, 0);
    ac = __builtin_amdgcn_mfma_f32_32x32x16_bf16(augA, augB, ac, 0, 0, 0);

    // ---- V frags (issued early; consumed by PV after barrier) ----
    const __bf16* vp =
        vtb + ((size_t)(bn * 64 + 32 * kh + ln31)) * 1024 + J0 + 8 * hlf;
    bf16x8 vf[4];
    vf[0] = *(const bf16x8*)(vp);
    vf[1] = *(const bf16x8*)(vp + 16);
    vf[2] = *(const bf16x8*)(vp + 32);
    vf[3] = *(const bf16x8*)(vp + 48);

    // ---- realign BD (1 bpermute/reg) + score + P write ----
#pragma unroll
    for (int rg = 0; rg < 16; ++rg) {
      int q_ = (rg & 3) + 8 * (rg >> 2) + 4 * hlf;
      int jsrc = (ln31 + q_ + 1) & 31;
      float selv = (jsrc > q_) ? bd[1][rg] : bd[0][rg];
      int addr = ((lane & 32) | ((ln31 + 31 - q_) & 31)) << 2;
      float bdr = __int_as_float(
          __builtin_amdgcn_ds_bpermute(addr, __float_as_int(selv)));
      float s = (ac[rg] + bdr) * 0.18033688f;  // 0.125*log2(e)
      float p = __builtin_amdgcn_exp2f(s);
      int sh = (rg & 3) + 8 * (rg >> 2);
      p = ((praw >> sh) & 1) ? 0.f : p;
      colsum[rg] += p;
      *(__bf16*)(spw + q_ * 128 + ((2 * (32 * kh + ln31)) ^ ((q_ & 7) << 4))) =
          (__bf16)p;
    }
    __syncthreads();  // P ready across kh-waves

    // ---- PV: full-j P x V (wave owns d-tile = kh) ----
#pragma unroll
    for (int kk = 0; kk < 4; ++kk) {
      bf16x8 pa = *(const bf16x8*)(
          spw + ln31 * 128 + ((32 * kk + 16 * hlf) ^ ((ln31 & 7) << 4)));
      oacc = __builtin_amdgcn_mfma_f32_32x32x16_bf16(pa, vf[kk], oacc, 0, 0, 0);
    }
    __syncthreads();  // P consumed; next-iter ring visible
  }

  // ---- epilogue: l reduce + merge + scale + store ----
#pragma unroll
  for (int m = 1; m <= 16; m <<= 1)
#pragma unroll
    for (int rg = 0; rg < 16; ++rg) colsum[rg] += __shfl_xor(colsum[rg], m);
  if (ln31 == 0) {
#pragma unroll
    for (int rg = 0; rg < 16; ++rg) sl[wave][hlf][rg] = colsum[rg];
  }
  __syncthreads();
#pragma unroll
  for (int rg = 0; rg < 16; ++rg) {
    float l = sl[2 * qh][hlf][rg] + sl[2 * qh + 1][hlf][rg];
    float rl = __fdividef(1.f, l);
    int qrow = 32 * qh + (rg & 3) + 8 * (rg >> 2) + 4 * hlf;
    av[((size_t)((z * 1024 + i0 + qrow) * 4 + b)) * 1024 + n * 64 + 32 * kh + ln31] =
        (__bf16)(oacc[rg] * rl);
  }
}

// ------------- residual add + LayerNorm (in-place on io) -------------
__global__ __launch_bounds__(256) void add_ln(float* __restrict__ io,
                                              const float* __restrict__ h,
                                              const float* __restrict__ g,
                                              const float* __restrict__ gam,
                                              const float* __restrict__ bet) {
  const size_t row = blockIdx.x;
  float* o = io + row * 1024;
  const float* x = (row < 4096) ? (h + row * 1024) : (g + (row - 4096) * 1024);
  const int t = threadIdx.x;
  float v[4];
  float s1 = 0.f, s2 = 0.f;
#pragma unroll
  for (int k = 0; k < 4; ++k) {
    int idx = t + 256 * k;
    v[k] = o[idx] + x[idx];
    s1 += v[k];
    s2 += v[k] * v[k];
  }
#pragma unroll
  for (int off = 32; off >= 1; off >>= 1) {
    s1 += __shfl_xor(s1, off);
    s2 += __shfl_xor(s2, off);
  }
  __shared__ float r1[4], r2[4];
  if ((t & 63) == 0) { r1[t >> 6] = s1; r2[t >> 6] = s2; }
  __syncthreads();
  s1 = r1[0] + r1[1] + r1[2] + r1[3];
  s2 = r2[0] + r2[1] + r2[2] + r2[3];
  float mean = s1 * (1.f / 1024.f);
  float var = s2 * (1.f / 1024.f) - mean * mean;
  float rstd = rsqrtf(fmaxf(var, 0.f) + 1e-12f);
#pragma unroll
  for (int k = 0; k < 4; ++k) {
    int idx = t + 256 * k;
    o[idx] = (v[k] - mean) * rstd * gam[idx] + bet[idx];
  }
}

extern "C" void kernel_launch(void* const* d_in, const int* in_sizes, int n_in,
                              void* d_out, int out_size, void* d_ws,
                              size_t ws_size, hipStream_t stream) {
  const float* h = (const float*)d_in[0];
  const float* g = (const float*)d_in[1];
  const float* mh = (const float*)d_in[2];
  const float* mg = (const float*)d_in[3];
  const float* r = (const float*)d_in[4];
  const float* seg = (const float*)d_in[5];
  const float* q_w = (const float*)d_in[6];
  const float* k_w = (const float*)d_in[7];
  const float* v_w = (const float*)d_in[8];
  const float* o_w = (const float*)d_in[9];
  const float* r_w = (const float*)d_in[10];
  const float* rrb = (const float*)d_in[11];
  const float* rsb = (const float*)d_in[12];
  const float* rwb = (const float*)d_in[13];
  const float* se = (const float*)d_in[14];
  const float* gam = (const float*)d_in[15];
  const float* bet = (const float*)d_in[16];
  float* out = (float*)d_out;

  // ---- ws layout ----
  char* w = (char*)d_ws;
  __bf16* hgb = (__bf16*)w;                 // 16MB [8192][1024]
  __bf16* vtb = (__bf16*)w;                 // aliases hgb (dead after q-GEMM)
  w += (size_t)16 << 20;
  __bf16* rb = (__bf16*)w;                  // 16MB
  __bf16* avb = (__bf16*)w;                 // aliases rb (dead after r-GEMM)
  w += (size_t)16 << 20;
  __bf16* qwt = (__bf16*)w; w += (size_t)2 << 20;
  __bf16* kwt = (__bf16*)w; w += (size_t)2 << 20;
  __bf16* vwt = (__bf16*)w; w += (size_t)2 << 20;
  __bf16* rwt = (__bf16*)w; w += (size_t)2 << 20;
  __bf16* owt = (__bf16*)w; w += (size_t)2 << 20;
  __bf16* qpb = (__bf16*)w; w += (size_t)16 << 20;  // [8192][1024]
  __bf16* khb = (__bf16*)w; w += (size_t)8 << 20;
  __bf16* vhb = (__bf16*)w; w += (size_t)8 << 20;
  __bf16* krb = (__bf16*)w; w += (size_t)16 << 20;
  unsigned int* mbits = (unsigned int*)w; w += (size_t)1 << 20;
  unsigned char* segvb = (unsigned char*)w; w += 4096;

  dim3 blk(256);

  cvt_bf16_k<<<4096, blk, 0, stream>>>(h, hgb, 4194304);
  cvt_bf16_k<<<4096, blk, 0, stream>>>(g, hgb + 4194304, 4194304);
  cvt_bf16_k<<<8192, blk, 0, stream>>>(r, rb, 8388608);
  cvt_bf16_k<<<1024, blk, 0, stream>>>(o_w, owt, 1048576);
  wtrans_k<<<dim3(16, 16), blk, 0, stream>>>(q_w, qwt);
  wtrans_k<<<dim3(16, 16), blk, 0, stream>>>(k_w, kwt);
  wtrans_k<<<dim3(16, 16), blk, 0, stream>>>(v_w, vwt);
  wtrans_k<<<dim3(16, 16), blk, 0, stream>>>(r_w, rwt);
  packbits_k<<<dim3(16, 64), blk, 0, stream>>>(mh, mg, mbits);
  segv_k<<<16, blk, 0, stream>>>(seg, segvb);

  gemm_mfma<true><<<dim3(8, 32), blk, 0, stream>>>(hgb, kwt, khb);
  gemm_mfma<true><<<dim3(8, 32), blk, 0, stream>>>(hgb, vwt, vhb);
  gemm_mfma<true><<<dim3(8, 64), blk, 0, stream>>>(rb, rwt, krb);
  gemm_mfma<true><<<dim3(8, 64), blk, 0, stream>>>(hgb, qwt, qpb);  // hgb dead after
  vtrans_k<<<dim3(8, 64), blk, 0, stream>>>(vhb, vtb);

  attn3<<<2048, blk, 0, stream>>>(qpb, khb, vtb, krb, mbits, segvb, se, rwb,
                                  rrb, rsb, avb);

  gemm_mfma<false><<<dim3(8, 64), blk, 0, stream>>>(avb, owt, out);
  add_ln<<<8192, blk, 0, stream>>>(out, h, g, gam, bet);
}